// Round 2
// baseline (102.126 us; speedup 1.0000x reference)
//
#include <hip/hip_runtime.h>

// RankNet pairwise loss, N=8192 fp32.
// Round 2: (1) launch only the 2112 active triangle blocks (1D packed grid,
// closed-form bx/iy from triangular prefix); (2) fixed 64-trip inner loop,
// separate no-mask path for fully-above-diagonal tiles; (3) fused final
// reduction via last-block-done (threadfence + device atomic, counter zeroed
// by captured hipMemsetAsync); (4) softplus in log2 domain (v_exp/v_log).

#define TJ 256  // j-tile width == blockDim.x
#define TI 64   // i-rows per block  (TJ/TI == 4, used by packed mapping)
#define LOG2E 1.44269504088896340736f
#define LN2   0.69314718055994530942f

__device__ __forceinline__ float fexp2(float x) { return __builtin_amdgcn_exp2f(x); }
__device__ __forceinline__ float flog2(float x) { return __builtin_amdgcn_logf(x); }

__global__ __launch_bounds__(TJ, 8) void rank_pairs_kernel(
    const float* __restrict__ pred, const float* __restrict__ target, int n,
    float* __restrict__ part_sum, unsigned int* __restrict__ part_cnt,
    unsigned int* __restrict__ done_cnt, int nblocks, float* __restrict__ out)
{
    int bx, iy, bid;
    if (gridDim.y == 1) {
        // packed triangular mapping: cum(bx) = 2*bx*(bx+1), active(bx) = 4*(bx+1)
        bid = (int)blockIdx.x;
        bx = (int)((sqrtf(8.f * (float)bid + 4.f) - 2.f) * 0.25f);
        while (2 * (bx + 1) * (bx + 2) <= bid) ++bx;
        while (2 * bx * (bx + 1) > bid) --bx;
        iy = bid - 2 * bx * (bx + 1);
    } else {
        bx = (int)blockIdx.x; iy = (int)blockIdx.y;
        bid = iy * (int)gridDim.x + bx;
    }

    const int j_base = bx * TJ;
    const int i_base = iy * TI;

    float sumH = 0.f, sumW = 0.f;
    unsigned int cnt = 0u;

    const int  j   = j_base + (int)threadIdx.x;
    const bool jin = (j < n);

    if (i_base < j_base + TJ && i_base < n) {
        const float pj = jin ? pred[j]   : 0.f;
        const float tj = jin ? target[j] : 0.f;

        if ((i_base + TI <= j_base) && (i_base + TI <= n) && jin) {
            // fully above diagonal: every (i,j) has i < j; no bounds checks
            #pragma unroll 16
            for (int k = 0; k < TI; ++k) {
                const int   i  = i_base + k;          // uniform -> s_load batch
                const float ti = target[i];
                const float pi = pred[i];
                const float td = ti - tj;
                const float pd = pi - pj;
                const float z  = (td > 0.f) ? -pd : pd;   // -sign(td)*pd
                const float u  = fexp2(-LOG2E * fabsf(z));
                const float w  = flog2(1.f + u);
                const bool  valid = (td != 0.f);
                sumH += valid ? fmaxf(z, 0.f) : 0.f;
                sumW += valid ? w : 0.f;
                cnt  += valid ? 1u : 0u;
            }
        } else {
            // diagonal-straddling or edge tile: full masking
            #pragma unroll 8
            for (int k = 0; k < TI; ++k) {
                const int i = i_base + k;
                if (i >= n) break;
                const float ti = target[i];
                const float pi = pred[i];
                const float td = ti - tj;
                const float pd = pi - pj;
                const float z  = (td > 0.f) ? -pd : pd;
                const float u  = fexp2(-LOG2E * fabsf(z));
                const float w  = flog2(1.f + u);
                const bool  valid = jin && (i < j) && (td != 0.f);
                sumH += valid ? fmaxf(z, 0.f) : 0.f;
                sumW += valid ? w : 0.f;
                cnt  += valid ? 1u : 0u;
            }
        }
    }

    float sum = sumH + LN2 * sumW;   // softplus recombine (beta = 1)

    // wave(64) shuffle reduce, then cross-wave via LDS
    #pragma unroll
    for (int off = 32; off > 0; off >>= 1) {
        sum += __shfl_down(sum, off, 64);
        cnt += __shfl_down(cnt, off, 64);
    }
    __shared__ float        s_s[TJ / 64];
    __shared__ unsigned int s_c[TJ / 64];
    __shared__ bool         s_last;
    const int lane = threadIdx.x & 63;
    const int wv   = threadIdx.x >> 6;
    if (lane == 0) { s_s[wv] = sum; s_c[wv] = cnt; }
    __syncthreads();
    if (threadIdx.x == 0) {
        float bs = 0.f; unsigned int bc = 0u;
        #pragma unroll
        for (int w = 0; w < TJ / 64; ++w) { bs += s_s[w]; bc += s_c[w]; }
        part_sum[bid] = bs;
        part_cnt[bid] = bc;
        __threadfence();                       // release partials (device scope)
        const unsigned int prev = atomicAdd(done_cnt, 1u);
        s_last = (prev == (unsigned int)(nblocks - 1));
    }
    __syncthreads();

    if (s_last) {
        __threadfence();                       // acquire all partials
        float fs = 0.f; unsigned int fc = 0u;
        for (int idx = (int)threadIdx.x; idx < nblocks; idx += TJ) {
            fs += part_sum[idx];
            fc += part_cnt[idx];
        }
        #pragma unroll
        for (int off = 32; off > 0; off >>= 1) {
            fs += __shfl_down(fs, off, 64);
            fc += __shfl_down(fc, off, 64);
        }
        if (lane == 0) { s_s[wv] = fs; s_c[wv] = fc; }
        __syncthreads();
        if (threadIdx.x == 0) {
            float bs = 0.f; unsigned int bc = 0u;
            #pragma unroll
            for (int w = 0; w < TJ / 64; ++w) { bs += s_s[w]; bc += s_c[w]; }
            out[0] = (bc > 0u) ? bs / (float)bc : 0.f;
        }
    }
}

extern "C" void kernel_launch(void* const* d_in, const int* in_sizes, int n_in,
                              void* d_out, int out_size, void* d_ws, size_t ws_size,
                              hipStream_t stream)
{
    const float* pred   = (const float*)d_in[0];
    const float* target = (const float*)d_in[1];
    float* out = (float*)d_out;
    const int n = in_sizes[0];

    dim3 grid;
    int nblocks;
    if (n % TJ == 0) {
        const int gx = n / TJ;                 // 32 for n=8192
        nblocks = 2 * gx * (gx + 1);           // 2112 active triangle blocks
        grid = dim3((unsigned)nblocks, 1);
    } else {
        const int gx = (n + TJ - 1) / TJ;
        const int gy = (n + TI - 1) / TI;
        nblocks = gx * gy;
        grid = dim3((unsigned)gx, (unsigned)gy);
    }

    float*        part_sum = (float*)d_ws;
    unsigned int* part_cnt = (unsigned int*)((char*)d_ws + (size_t)nblocks * sizeof(float));
    unsigned int* done_cnt = (unsigned int*)((char*)d_ws + (size_t)2 * nblocks * sizeof(float));

    hipMemsetAsync(done_cnt, 0, sizeof(unsigned int), stream);
    rank_pairs_kernel<<<grid, TJ, 0, stream>>>(pred, target, n, part_sum, part_cnt,
                                               done_cnt, nblocks, out);
}